// Round 5
// baseline (298.893 us; speedup 1.0000x reference)
//
#include <hip/hip_runtime.h>
#include <stdint.h>

// B=4, T=2048, C=1024, H=16, D=64, R=32
// Pipeline: cvt -> qkv_gemm(BK=32, +RoPE/scale/mask-fold) -> attn -> out_gemm

typedef __attribute__((ext_vector_type(8))) short bf16x8;   // 8 bf16 (4 VGPRs)
typedef __attribute__((ext_vector_type(4))) float f32x4;    // MFMA accumulator
typedef __attribute__((ext_vector_type(4))) short short4v;  // 8-byte packed store
typedef __attribute__((ext_vector_type(2))) uint32_t uint2v;

#define MFMA16(a, b, c) __builtin_amdgcn_mfma_f32_16x16x32_bf16((a), (b), (c), 0, 0, 0)

#if __has_builtin(__builtin_amdgcn_exp2f)
#define FEXP(x) __builtin_amdgcn_exp2f(x)
#define QSCALE 0.18033688011112042f  // 0.125 * log2(e)
#else
#define FEXP(x) __expf(x)
#define QSCALE 0.125f
#endif

static __device__ __forceinline__ short f2bf(float f) {
  union { float fv; uint32_t u; } v; v.fv = f;
  uint32_t r = v.u + 0x7FFFu + ((v.u >> 16) & 1u);  // RNE
  return (short)(r >> 16);
}

// pack two fp32 -> two bf16 (truncation) in one v_perm_b32
static __device__ __forceinline__ uint32_t pack_trunc(float a, float b) {
  union { float f; uint32_t u; } ua, ub;
  ua.f = a; ub.f = b;
#if __has_builtin(__builtin_amdgcn_perm)
  return __builtin_amdgcn_perm(ub.u, ua.u, 0x07060302u);
#else
  return (ub.u & 0xFFFF0000u) | (ua.u >> 16);
#endif
}

typedef __attribute__((address_space(1))) void as1_void;
typedef __attribute__((address_space(3))) void as3_void;
static __device__ __forceinline__ void gld_lds16(const void* g, void* l) {
  __builtin_amdgcn_global_load_lds((as1_void*)g, (as3_void*)l, 16, 0, 0);
}

// ---------------------------------------------------------------------------
// Kernel 1: fp32 -> bf16 conversion for x, Wq, Wk, Wv, Wo
// ---------------------------------------------------------------------------
__global__ __launch_bounds__(256) void cvt_kernel(
    const float* x, const float* wq, const float* wk, const float* wv,
    const float* wo,
    short* xb, short* wqb, short* wkb, short* wvb, short* wob) {
  int64_t g = (int64_t)blockIdx.x * 256 + threadIdx.x;  // unit = 4 floats
  const int64_t NX = 8388608 / 4, NW = 1048576 / 4;
  const float* src;
  short* dst;
  int64_t i;
  if (g < NX)               { src = x;  dst = xb;  i = g; }
  else if (g < NX + NW)     { src = wq; dst = wqb; i = g - NX; }
  else if (g < NX + 2 * NW) { src = wk; dst = wkb; i = g - NX - NW; }
  else if (g < NX + 3 * NW) { src = wv; dst = wvb; i = g - NX - 2 * NW; }
  else                      { src = wo; dst = wob; i = g - NX - 3 * NW; }
  float4 v = ((const float4*)src)[i];
  short4v o;
  o[0] = f2bf(v.x); o[1] = f2bf(v.y); o[2] = f2bf(v.z); o[3] = f2bf(v.w);
  *(short4v*)&dst[i * 4] = o;
}

// ---------------------------------------------------------------------------
// Kernel 2: QKV projection GEMM (M=8192, N=1024, K=1024), BK=32.
//   128x128 tile, 4 waves. Q: scaled by QSCALE; K,V: masked rows zeroed.
//   Q,K written [bh][t][64] bf16; V written [bh][64][t] bf16 (transposed).
// ---------------------------------------------------------------------------
__global__ __launch_bounds__(256) void qkv_gemm(
    const short* __restrict__ Xb,
    const short* __restrict__ Wq, const short* __restrict__ Wk,
    const short* __restrict__ Wv,
    const float* __restrict__ bq, const float* __restrict__ bk,
    const float* __restrict__ bv,
    const float* __restrict__ rope, const int* __restrict__ mask,
    short* __restrict__ Qh, short* __restrict__ Kh, short* __restrict__ Vt) {
  __shared__ __align__(16) short As[128 * 32];  // 8 KB
  __shared__ __align__(16) short Bs[128 * 32];  // 8 KB

  const int t = threadIdx.x;
  const int lane = t & 63;
  const int wave = t >> 6;
  const int c = lane & 15;
  const int quad = lane >> 4;
  const int m0 = blockIdx.x * 128;
  const int n0 = blockIdx.y * 128;
  const int mat = blockIdx.z;
  const short* Wg = (mat == 0) ? Wq : (mat == 1) ? Wk : Wv;
  const float* bias = (mat == 0) ? bq : (mat == 1) ? bk : bv;

  f32x4 zero4 = {0.f, 0.f, 0.f, 0.f};
  f32x4 acc[4][4];
#pragma unroll
  for (int i = 0; i < 4; ++i)
#pragma unroll
    for (int j = 0; j < 4; ++j) acc[i][j] = zero4;

  const int wm = wave & 1, wn = wave >> 1;

  const int srow = t >> 2;
  const int gc = ((t & 3) - (srow >> 2)) & 3;
  const short* gA = Xb + (size_t)(m0 + srow) * 1024 + gc * 8;
  const short* gB = Wg + (size_t)(n0 + srow) * 1024 + gc * 8;
  short* lA = &As[t * 8];
  short* lB = &Bs[t * 8];

  for (int k0 = 0; k0 < 1024; k0 += 32) {
    gld_lds16(gA + k0, lA);
    gld_lds16(gA + k0 + 65536, lA + 2048);  // +64 rows
    gld_lds16(gB + k0, lB);
    gld_lds16(gB + k0 + 65536, lB + 2048);
    __syncthreads();

    bf16x8 af[4], bfr[4];
#pragma unroll
    for (int i = 0; i < 4; ++i) {
      int mr = wm * 64 + i * 16 + c;
      af[i] = *(const bf16x8*)&As[mr * 32 + (((quad + (mr >> 2)) & 3) * 8)];
      int nr = wn * 64 + i * 16 + c;
      bfr[i] = *(const bf16x8*)&Bs[nr * 32 + (((quad + (nr >> 2)) & 3) * 8)];
    }
#pragma unroll
    for (int i = 0; i < 4; ++i)
#pragma unroll
      for (int j = 0; j < 4; ++j) acc[i][j] = MFMA16(af[i], bfr[j], acc[i][j]);
    __syncthreads();
  }

  // ---- epilogue: C/D layout col=lane&15, row=quad*4+reg ----
  const int nb = n0 + wn * 64;  // wave's 64 cols == one head
  const int hcol = nb >> 6;
  float bj[4];
#pragma unroll
  for (int j = 0; j < 4; ++j) bj[j] = bias[nb + j * 16 + c];
  const int bidx = m0 >> 11;
  const int tbase = (m0 & 2047) + wm * 64 + quad * 4;
  const int* mrow = mask + bidx * 2048;

  if (mat < 2) {
    short* Og = (mat == 0) ? Qh : Kh;
    size_t hb = (size_t)(bidx * 16 + hcol) * 2048;
#pragma unroll
    for (int i = 0; i < 4; ++i) {
#pragma unroll
      for (int r = 0; r < 4; ++r) {
        int tp = tbase + i * 16 + r;
        float f = (mat == 0) ? QSCALE : (mrow[tp] ? 1.0f : 0.0f);
        float cosv = rope[tp * 32 + c];
        float sinv = rope[65536 + tp * 32 + c];
        float v0 = acc[i][0][r] + bj[0];
        float v1 = acc[i][1][r] + bj[1];
        float v2 = acc[i][2][r] + bj[2];
        float v3 = acc[i][3][r] + bj[3];
        size_t base = (hb + tp) * 64;
        Og[base + c]      = f2bf((v0 * cosv - v1 * sinv) * f);
        Og[base + 16 + c] = f2bf((v1 * cosv + v0 * sinv) * f);
        Og[base + 32 + c] = f2bf(v2 * f);
        Og[base + 48 + c] = f2bf(v3 * f);
      }
    }
  } else {
    size_t hb = (size_t)(bidx * 16 + hcol) * 64;
#pragma unroll
    for (int i = 0; i < 4; ++i) {
      int tp = tbase + i * 16;  // multiple of 4
      int4 mv = *(const int4*)&mrow[tp];
      float fr[4];
      fr[0] = mv.x ? 1.f : 0.f; fr[1] = mv.y ? 1.f : 0.f;
      fr[2] = mv.z ? 1.f : 0.f; fr[3] = mv.w ? 1.f : 0.f;
#pragma unroll
      for (int j = 0; j < 4; ++j) {
        short4v pv;
#pragma unroll
        for (int r = 0; r < 4; ++r) pv[r] = f2bf((acc[i][j][r] + bj[j]) * fr[r]);
        size_t base = (hb + j * 16 + c) * 2048 + tp;
        *(short4v*)&Vt[base] = pv;
      }
    }
  }
}

// ---------------------------------------------------------------------------
// Kernel 3: attention, static softmax. 256 q-rows/block (64 per wave),
//   double-buffered K/V staging: loads for chunk c+1 issue right after the
//   barrier that publishes chunk c, so the vmcnt(0)+barrier drain at the
//   next iteration waits on loads that are ~one compute-phase old.
//   S^T = K*Q^T -> p = exp2(s) -> P(bf16, per-wave, 2 halves) -> O^T = V^T*P^T.
//   l via ones-A MFMA. Grid (8,64) = 512 blocks = exactly 2/CU.
// ---------------------------------------------------------------------------
__global__ __launch_bounds__(256, 2) void attn_kernel(
    const short* __restrict__ Qh, const short* __restrict__ Kh,
    const short* __restrict__ Vt, const int* __restrict__ mask,
    short* __restrict__ Og) {
  __shared__ __align__(16) short Ks[2][64 * 64];  // 16 KB
  __shared__ __align__(16) short Vs[2][64 * 64];  // 16 KB
  __shared__ __align__(16) short Pl[4][32 * 64];  // 16 KB, per-wave
  __shared__ float nmw[4];

  const int t = threadIdx.x;
  const int lane = t & 63;
  const int wave = t >> 6;
  const int c = lane & 15;
  const int quad = lane >> 4;
  const int qt = blockIdx.x;   // 0..7 (256 q rows each)
  const int bh = blockIdx.y;   // 0..63
  const int bidx = bh >> 4;
  const short* Qg = Qh + ((size_t)bh * 2048 + qt * 256) * 64;
  const short* Kg = Kh + (size_t)bh * 2048 * 64;
  const short* Vg = Vt + (size_t)bh * 64 * 2048;

  // count masked keys for this batch (once per block)
  {
    const int4* mr = (const int4*)(mask + bidx * 2048);
    int4 a = mr[t * 2], b = mr[t * 2 + 1];
    int cnt = (a.x == 0) + (a.y == 0) + (a.z == 0) + (a.w == 0) +
              (b.x == 0) + (b.y == 0) + (b.z == 0) + (b.w == 0);
    cnt += __shfl_xor(cnt, 1);  cnt += __shfl_xor(cnt, 2);
    cnt += __shfl_xor(cnt, 4);  cnt += __shfl_xor(cnt, 8);
    cnt += __shfl_xor(cnt, 16); cnt += __shfl_xor(cnt, 32);
    if (lane == 0) nmw[wave] = (float)cnt;
  }

  // Q fragments (B-operand), loop-invariant; wave covers 64 q rows (it 0..3)
  bf16x8 qf[2][4];
#pragma unroll
  for (int ks = 0; ks < 2; ++ks)
#pragma unroll
    for (int it = 0; it < 4; ++it)
      qf[ks][it] =
          *(const bf16x8*)&Qg[(wave * 64 + it * 16 + c) * 64 + ks * 32 + quad * 8];

  const bf16x8 ones = {0x3F80, 0x3F80, 0x3F80, 0x3F80,
                       0x3F80, 0x3F80, 0x3F80, 0x3F80};  // bf16 1.0 x8

  f32x4 zero4 = {0.f, 0.f, 0.f, 0.f};
  f32x4 O[4][4];
#pragma unroll
  for (int dt = 0; dt < 4; ++dt)
#pragma unroll
    for (int it = 0; it < 4; ++it) O[dt][it] = zero4;
  f32x4 Ol[4] = {zero4, zero4, zero4, zero4};

  const int krow0 = t >> 3;
  const int klc = (t & 7) ^ (krow0 & 7);
  const short* gk0 = Kg + (size_t)krow0 * 64 + klc * 8;
  const short* gv0 = Vg + (size_t)krow0 * 2048 + klc * 8;
  short* Pw = &Pl[wave][0];

  // prologue: stage chunk 0 into buffer 0
  gld_lds16(gk0, &Ks[0][t * 8]);
  gld_lds16(gk0 + 32 * 64, &Ks[0][t * 8 + 2048]);
  gld_lds16(gv0, &Vs[0][t * 8]);
  gld_lds16(gv0 + 32 * 2048, &Vs[0][t * 8 + 2048]);

  for (int ci = 0; ci < 32; ++ci) {
    __syncthreads();  // drains chunk-ci loads (issued one compute-phase ago)
    if (ci < 31) {    // issue chunk ci+1 into the other buffer, then compute
      int cn = (ci + 1) * 64;
      int nb = (ci + 1) & 1;
      gld_lds16(gk0 + (size_t)cn * 64, &Ks[nb][t * 8]);
      gld_lds16(gk0 + (size_t)(cn + 32) * 64, &Ks[nb][t * 8 + 2048]);
      gld_lds16(gv0 + cn, &Vs[nb][t * 8]);
      gld_lds16(gv0 + cn + 32 * 2048, &Vs[nb][t * 8 + 2048]);
    }
    const short* ksb = &Ks[ci & 1][0];
    const short* vsb = &Vs[ci & 1][0];

#pragma unroll
    for (int h = 0; h < 2; ++h) {  // two q-halves (it = 2h, 2h+1)
      // S^T = K * Q^T : rows=tk, cols=q; ks=0 slice takes zero C
      f32x4 St[4][2];
#pragma unroll
      for (int jt = 0; jt < 4; ++jt) {
        bf16x8 ak =
            *(const bf16x8*)&ksb[(jt * 16 + c) * 64 + ((quad ^ (c & 7)) * 8)];
        St[jt][0] = MFMA16(ak, qf[0][h * 2 + 0], zero4);
        St[jt][1] = MFMA16(ak, qf[0][h * 2 + 1], zero4);
      }
#pragma unroll
      for (int jt = 0; jt < 4; ++jt) {
        bf16x8 ak =
            *(const bf16x8*)&ksb[(jt * 16 + c) * 64 + (((4 + quad) ^ (c & 7)) * 8)];
        St[jt][0] = MFMA16(ak, qf[1][h * 2 + 0], St[jt][0]);
        St[jt][1] = MFMA16(ak, qf[1][h * 2 + 1], St[jt][1]);
      }

      // p = exp2(s); pack to bf16 (trunc) into per-wave swizzled P
#pragma unroll
      for (int itl = 0; itl < 2; ++itl) {
#pragma unroll
        for (int jt = 0; jt < 4; ++jt) {
          float p0 = FEXP(St[jt][itl][0]);
          float p1 = FEXP(St[jt][itl][1]);
          float p2 = FEXP(St[jt][itl][2]);
          float p3 = FEXP(St[jt][itl][3]);
          uint2v pk;
          pk[0] = pack_trunc(p0, p1);
          pk[1] = pack_trunc(p2, p3);
          *(uint2v*)&Pw[(itl * 16 + c) * 64 +
                        (((jt * 2 + (quad >> 1)) ^ (c & 7)) * 8) +
                        (quad & 1) * 4] = pk;
        }
      }
      asm volatile("s_waitcnt lgkmcnt(0)" ::: "memory");  // own-wave P visible

      // O^T += V^T * P^T ; l += 1^T * P^T
#pragma unroll
      for (int ks = 0; ks < 2; ++ks) {
        bf16x8 bp0 =
            *(const bf16x8*)&Pw[c * 64 + (((ks * 4 + quad) ^ (c & 7)) * 8)];
        bf16x8 bp1 =
            *(const bf16x8*)&Pw[(16 + c) * 64 + (((ks * 4 + quad) ^ (c & 7)) * 8)];
        Ol[h * 2 + 0] = MFMA16(ones, bp0, Ol[h * 2 + 0]);
        Ol[h * 2 + 1] = MFMA16(ones, bp1, Ol[h * 2 + 1]);
#pragma unroll
        for (int dt = 0; dt < 4; ++dt) {
          bf16x8 av =
              *(const bf16x8*)&vsb[(dt * 16 + c) * 64 + (((4 * ks + quad) ^ (c & 7)) * 8)];
          O[dt][h * 2 + 0] = MFMA16(av, bp0, O[dt][h * 2 + 0]);
          O[dt][h * 2 + 1] = MFMA16(av, bp1, O[dt][h * 2 + 1]);
        }
      }
    }
  }

  float nm = nmw[0] + nmw[1] + nmw[2] + nmw[3];
#pragma unroll
  for (int it = 0; it < 4; ++it) {
    // Ol rows all identical (ones A): this lane's col c -> l[q]
    float inv = 1.0f / (Ol[it][0] - nm);  // remove masked keys' exp2(0)=1
    int tq = qt * 256 + wave * 64 + it * 16 + c;
    size_t rb = ((size_t)bidx * 2048 + tq) * 1024 + (size_t)(bh & 15) * 64;
#pragma unroll
    for (int dt = 0; dt < 4; ++dt) {
      short4v ov;
#pragma unroll
      for (int r = 0; r < 4; ++r) ov[r] = f2bf(O[dt][it][r] * inv);
      *(short4v*)&Og[rb + dt * 16 + quad * 4] = ov;
    }
  }
}

// ---------------------------------------------------------------------------
// Kernel 4: output projection GEMM: out = attout @ Wo^T + bo (fp32 out).
//   64x128 tile, BK=32 -> 1024 blocks, 12 KB LDS.
// ---------------------------------------------------------------------------
__global__ __launch_bounds__(256) void out_gemm(
    const short* __restrict__ Ab, const short* __restrict__ Wob,
    const float* __restrict__ bo, float* __restrict__ out) {
  __shared__ __align__(16) short As[64 * 32];   // 4 KB
  __shared__ __align__(16) short Bs[128 * 32];  // 8 KB

  const int t = threadIdx.x;
  const int lane = t & 63;
  const int wave = t >> 6;
  const int c = lane & 15;
  const int quad = lane >> 4;
  const int m0 = blockIdx.x * 64;
  const int n0 = blockIdx.y * 128;

  f32x4 zero4 = {0.f, 0.f, 0.f, 0.f};
  f32x4 acc[4][2];
#pragma unroll
  for (int i = 0; i < 4; ++i) {
    acc[i][0] = zero4;
    acc[i][1] = zero4;
  }

  const int srow = t >> 2;
  const int gc = ((t & 3) - (srow >> 2)) & 3;
  const short* gA = Ab + (size_t)(m0 + srow) * 1024 + gc * 8;
  const short* gB = Wob + (size_t)(n0 + srow) * 1024 + gc * 8;

  for (int k0 = 0; k0 < 1024; k0 += 32) {
    gld_lds16(gA + k0, &As[t * 8]);
    gld_lds16(gB + k0, &Bs[t * 8]);
    gld_lds16(gB + k0 + 65536, &Bs[t * 8 + 2048]);
    __syncthreads();

    bf16x8 af[4], bfr[2];
#pragma unroll
    for (int i = 0; i < 4; ++i) {
      int mr = i * 16 + c;
      af[i] = *(const bf16x8*)&As[mr * 32 + (((quad + (mr >> 2)) & 3) * 8)];
    }
#pragma unroll
    for (int j = 0; j < 2; ++j) {
      int nr = wave * 32 + j * 16 + c;
      bfr[j] = *(const bf16x8*)&Bs[nr * 32 + (((quad + (nr >> 2)) & 3) * 8)];
    }
#pragma unroll
    for (int i = 0; i < 4; ++i) {
      acc[i][0] = MFMA16(af[i], bfr[0], acc[i][0]);
      acc[i][1] = MFMA16(af[i], bfr[1], acc[i][1]);
    }
    __syncthreads();
  }

  const int nb = n0 + wave * 32;
  float bj[2];
  bj[0] = bo[nb + c];
  bj[1] = bo[nb + 16 + c];
#pragma unroll
  for (int i = 0; i < 4; ++i) {
    int m = m0 + i * 16 + quad * 4;
#pragma unroll
    for (int r = 0; r < 4; ++r) {
      float* orow = out + (size_t)(m + r) * 1024 + nb;
      orow[c]      = acc[i][0][r] + bj[0];
      orow[16 + c] = acc[i][1][r] + bj[1];
    }
  }
}

// ---------------------------------------------------------------------------
extern "C" void kernel_launch(void* const* d_in, const int* in_sizes, int n_in,
                              void* d_out, int out_size, void* d_ws,
                              size_t ws_size, hipStream_t stream) {
  const float* x    = (const float*)d_in[0];
  const float* rope = (const float*)d_in[1];
  const int*   mask = (const int*)d_in[2];
  const float* Wq   = (const float*)d_in[3];
  const float* bq   = (const float*)d_in[4];
  const float* Wk   = (const float*)d_in[5];
  const float* bk   = (const float*)d_in[6];
  const float* Wv   = (const float*)d_in[7];
  const float* bv   = (const float*)d_in[8];
  const float* Wo   = (const float*)d_in[9];
  const float* bo   = (const float*)d_in[10];
  float* out = (float*)d_out;

  char* ws = (char*)d_ws;
  short* xb  = (short*)(ws);               // 16 MB; reused as attout later
  short* wqb = (short*)(ws + 16777216);    // 2 MB each
  short* wkb = (short*)(ws + 18874368);
  short* wvb = (short*)(ws + 20971520);
  short* wob = (short*)(ws + 23068672);
  short* Qh  = (short*)(ws + 25198592);    // 16 MB  [bh][t][64]
  short* Kh  = (short*)(ws + 41975808);    // 16 MB  [bh][t][64]
  short* Vt  = (short*)(ws + 58753024);    // 16 MB  [bh][64][t]
  short* att = xb;  // safe: xb consumed by qkv_gemm before attn writes

  cvt_kernel<<<12288, 256, 0, stream>>>(x, Wq, Wk, Wv, Wo, xb, wqb, wkb, wvb,
                                        wob);
  qkv_gemm<<<dim3(64, 8, 3), 256, 0, stream>>>(xb, wqb, wkb, wvb, bq, bk, bv,
                                               rope, mask, Qh, Kh, Vt);
  attn_kernel<<<dim3(8, 64), 256, 0, stream>>>(Qh, Kh, Vt, mask, att);
  out_gemm<<<dim3(128, 8), 256, 0, stream>>>(att, wob, bo, out);
}

// Round 6
// 280.714 us; speedup vs baseline: 1.0648x; 1.0648x over previous
//
#include <hip/hip_runtime.h>
#include <stdint.h>

// B=4, T=2048, C=1024, H=16, D=64, R=32
// Pipeline: cvt -> qkv3_gemm(fused QKV, dbuf) -> attn -> out_gemm(dbuf)

typedef __attribute__((ext_vector_type(8))) short bf16x8;   // 8 bf16 (4 VGPRs)
typedef __attribute__((ext_vector_type(4))) float f32x4;    // MFMA accumulator
typedef __attribute__((ext_vector_type(4))) short short4v;  // 8-byte packed store
typedef __attribute__((ext_vector_type(2))) uint32_t uint2v;

#define MFMA16(a, b, c) __builtin_amdgcn_mfma_f32_16x16x32_bf16((a), (b), (c), 0, 0, 0)

#if __has_builtin(__builtin_amdgcn_exp2f)
#define FEXP(x) __builtin_amdgcn_exp2f(x)
#define QSCALE 0.18033688011112042f  // 0.125 * log2(e)
#else
#define FEXP(x) __expf(x)
#define QSCALE 0.125f
#endif

static __device__ __forceinline__ short f2bf(float f) {
  union { float fv; uint32_t u; } v; v.fv = f;
  uint32_t r = v.u + 0x7FFFu + ((v.u >> 16) & 1u);  // RNE
  return (short)(r >> 16);
}

// pack two fp32 -> two bf16 (truncation) in one v_perm_b32
static __device__ __forceinline__ uint32_t pack_trunc(float a, float b) {
  union { float f; uint32_t u; } ua, ub;
  ua.f = a; ub.f = b;
#if __has_builtin(__builtin_amdgcn_perm)
  return __builtin_amdgcn_perm(ub.u, ua.u, 0x07060302u);
#else
  return (ub.u & 0xFFFF0000u) | (ua.u >> 16);
#endif
}

typedef __attribute__((address_space(1))) void as1_void;
typedef __attribute__((address_space(3))) void as3_void;
static __device__ __forceinline__ void gld_lds16(const void* g, void* l) {
  __builtin_amdgcn_global_load_lds((as1_void*)g, (as3_void*)l, 16, 0, 0);
}

// ---------------------------------------------------------------------------
// Kernel 1: fp32 -> bf16 conversion for x, Wq, Wk, Wv, Wo
// ---------------------------------------------------------------------------
__global__ __launch_bounds__(256) void cvt_kernel(
    const float* x, const float* wq, const float* wk, const float* wv,
    const float* wo,
    short* xb, short* wqb, short* wkb, short* wvb, short* wob) {
  int64_t g = (int64_t)blockIdx.x * 256 + threadIdx.x;  // unit = 4 floats
  const int64_t NX = 8388608 / 4, NW = 1048576 / 4;
  const float* src;
  short* dst;
  int64_t i;
  if (g < NX)               { src = x;  dst = xb;  i = g; }
  else if (g < NX + NW)     { src = wq; dst = wqb; i = g - NX; }
  else if (g < NX + 2 * NW) { src = wk; dst = wkb; i = g - NX - NW; }
  else if (g < NX + 3 * NW) { src = wv; dst = wvb; i = g - NX - 2 * NW; }
  else                      { src = wo; dst = wob; i = g - NX - 3 * NW; }
  float4 v = ((const float4*)src)[i];
  short4v o;
  o[0] = f2bf(v.x); o[1] = f2bf(v.y); o[2] = f2bf(v.z); o[3] = f2bf(v.w);
  *(short4v*)&dst[i * 4] = o;
}

// ---------------------------------------------------------------------------
// Kernel 2: fused QKV projection (M=8192, N=1024 x3, K=1024), BK=32.
//   One A-tile stage feeds 3 B-tiles: 48 MFMA per barrier. Double-buffered
//   staging issued right after the barrier (loads age one compute phase
//   before the next barrier's vmcnt(0) drain).
//   Q: scaled by QSCALE; K,V: masked rows zeroed.
//   Q,K written [bh][t][64] bf16; V written [bh][64][t] bf16 (transposed).
// ---------------------------------------------------------------------------
__global__ __launch_bounds__(256, 2) void qkv3_gemm(
    const short* __restrict__ Xb,
    const short* __restrict__ Wq, const short* __restrict__ Wk,
    const short* __restrict__ Wv,
    const float* __restrict__ bq, const float* __restrict__ bk,
    const float* __restrict__ bv,
    const float* __restrict__ rope, const int* __restrict__ mask,
    short* __restrict__ Qh, short* __restrict__ Kh, short* __restrict__ Vt) {
  __shared__ __align__(16) short As[2][128 * 32];     // 16 KB
  __shared__ __align__(16) short Bs[2][3][128 * 32];  // 48 KB

  const int t = threadIdx.x;
  const int lane = t & 63;
  const int wave = t >> 6;
  const int c = lane & 15;
  const int quad = lane >> 4;
  const int m0 = blockIdx.x * 128;
  const int n0 = blockIdx.y * 128;

  f32x4 zero4 = {0.f, 0.f, 0.f, 0.f};
  f32x4 acc[3][4][4];
#pragma unroll
  for (int m = 0; m < 3; ++m)
#pragma unroll
    for (int i = 0; i < 4; ++i)
#pragma unroll
      for (int j = 0; j < 4; ++j) acc[m][i][j] = zero4;

  const int wm = wave & 1, wn = wave >> 1;

  const int srow = t >> 2;
  const int gc = ((t & 3) - (srow >> 2)) & 3;
  const short* gA = Xb + (size_t)(m0 + srow) * 1024 + gc * 8;
  const short* gW0 = Wq + (size_t)(n0 + srow) * 1024 + gc * 8;
  const short* gW1 = Wk + (size_t)(n0 + srow) * 1024 + gc * 8;
  const short* gW2 = Wv + (size_t)(n0 + srow) * 1024 + gc * 8;

#define QKV_STAGE(buf, k0)                                  \
  do {                                                      \
    gld_lds16(gA + (k0), &As[buf][t * 8]);                  \
    gld_lds16(gA + (k0) + 65536, &As[buf][t * 8 + 2048]);   \
    gld_lds16(gW0 + (k0), &Bs[buf][0][t * 8]);              \
    gld_lds16(gW0 + (k0) + 65536, &Bs[buf][0][t * 8 + 2048]); \
    gld_lds16(gW1 + (k0), &Bs[buf][1][t * 8]);              \
    gld_lds16(gW1 + (k0) + 65536, &Bs[buf][1][t * 8 + 2048]); \
    gld_lds16(gW2 + (k0), &Bs[buf][2][t * 8]);              \
    gld_lds16(gW2 + (k0) + 65536, &Bs[buf][2][t * 8 + 2048]); \
  } while (0)

  QKV_STAGE(0, 0);

  for (int ki = 0; ki < 32; ++ki) {
    __syncthreads();  // drains buf[ki&1] loads (issued one compute phase ago)
    if (ki < 31) QKV_STAGE((ki + 1) & 1, (ki + 1) * 32);

    const short* as = &As[ki & 1][0];
    bf16x8 af[4];
#pragma unroll
    for (int i = 0; i < 4; ++i) {
      int mr = wm * 64 + i * 16 + c;
      af[i] = *(const bf16x8*)&as[mr * 32 + (((quad + (mr >> 2)) & 3) * 8)];
    }
#pragma unroll
    for (int m = 0; m < 3; ++m) {
      const short* bs = &Bs[ki & 1][m][0];
      bf16x8 bfr[4];
#pragma unroll
      for (int j = 0; j < 4; ++j) {
        int nr = wn * 64 + j * 16 + c;
        bfr[j] = *(const bf16x8*)&bs[nr * 32 + (((quad + (nr >> 2)) & 3) * 8)];
      }
#pragma unroll
      for (int i = 0; i < 4; ++i)
#pragma unroll
        for (int j = 0; j < 4; ++j)
          acc[m][i][j] = MFMA16(af[i], bfr[j], acc[m][i][j]);
    }
  }
#undef QKV_STAGE

  // ---- epilogue: C/D layout col=lane&15, row=quad*4+reg ----
  const int nb = n0 + wn * 64;  // wave's 64 cols == one head
  const int hcol = nb >> 6;
  const int bidx = m0 >> 11;
  const int tbase = (m0 & 2047) + wm * 64 + quad * 4;
  const int* mrow = mask + bidx * 2048;

  // Q (mat 0) and K (mat 1): [bh][t][64] with RoPE
#pragma unroll
  for (int mat = 0; mat < 2; ++mat) {
    short* Og = (mat == 0) ? Qh : Kh;
    const float* bias = (mat == 0) ? bq : bk;
    float bj[4];
#pragma unroll
    for (int j = 0; j < 4; ++j) bj[j] = bias[nb + j * 16 + c];
    size_t hb = (size_t)(bidx * 16 + hcol) * 2048;
#pragma unroll
    for (int i = 0; i < 4; ++i) {
#pragma unroll
      for (int r = 0; r < 4; ++r) {
        int tp = tbase + i * 16 + r;
        float f = (mat == 0) ? QSCALE : (mrow[tp] ? 1.0f : 0.0f);
        float cosv = rope[tp * 32 + c];
        float sinv = rope[65536 + tp * 32 + c];
        float v0 = acc[mat][i][0][r] + bj[0];
        float v1 = acc[mat][i][1][r] + bj[1];
        float v2 = acc[mat][i][2][r] + bj[2];
        float v3 = acc[mat][i][3][r] + bj[3];
        size_t base = (hb + tp) * 64;
        Og[base + c]      = f2bf((v0 * cosv - v1 * sinv) * f);
        Og[base + 16 + c] = f2bf((v1 * cosv + v0 * sinv) * f);
        Og[base + 32 + c] = f2bf(v2 * f);
        Og[base + 48 + c] = f2bf(v3 * f);
      }
    }
  }
  // V (mat 2): transposed [bh][d][t], masked t zeroed
  {
    float bj[4];
#pragma unroll
    for (int j = 0; j < 4; ++j) bj[j] = bv[nb + j * 16 + c];
    size_t hb = (size_t)(bidx * 16 + hcol) * 64;
#pragma unroll
    for (int i = 0; i < 4; ++i) {
      int tp = tbase + i * 16;  // multiple of 4
      int4 mv = *(const int4*)&mrow[tp];
      float fr[4];
      fr[0] = mv.x ? 1.f : 0.f; fr[1] = mv.y ? 1.f : 0.f;
      fr[2] = mv.z ? 1.f : 0.f; fr[3] = mv.w ? 1.f : 0.f;
#pragma unroll
      for (int j = 0; j < 4; ++j) {
        short4v pv;
#pragma unroll
        for (int r = 0; r < 4; ++r)
          pv[r] = f2bf((acc[2][i][j][r] + bj[j]) * fr[r]);
        size_t base = (hb + j * 16 + c) * 2048 + tp;
        *(short4v*)&Vt[base] = pv;
      }
    }
  }
}

// ---------------------------------------------------------------------------
// Kernel 3: attention, static softmax. 256 q-rows/block (64 per wave),
//   double-buffered K/V staging. S^T = K*Q^T -> p = exp2(s) -> P(bf16) ->
//   O^T = V^T*P^T; l via ones-A MFMA. Grid (8,64) = 512 blocks.
// ---------------------------------------------------------------------------
__global__ __launch_bounds__(256, 2) void attn_kernel(
    const short* __restrict__ Qh, const short* __restrict__ Kh,
    const short* __restrict__ Vt, const int* __restrict__ mask,
    short* __restrict__ Og) {
  __shared__ __align__(16) short Ks[2][64 * 64];  // 16 KB
  __shared__ __align__(16) short Vs[2][64 * 64];  // 16 KB
  __shared__ __align__(16) short Pl[4][32 * 64];  // 16 KB, per-wave
  __shared__ float nmw[4];

  const int t = threadIdx.x;
  const int lane = t & 63;
  const int wave = t >> 6;
  const int c = lane & 15;
  const int quad = lane >> 4;
  const int qt = blockIdx.x;   // 0..7 (256 q rows each)
  const int bh = blockIdx.y;   // 0..63
  const int bidx = bh >> 4;
  const short* Qg = Qh + ((size_t)bh * 2048 + qt * 256) * 64;
  const short* Kg = Kh + (size_t)bh * 2048 * 64;
  const short* Vg = Vt + (size_t)bh * 64 * 2048;

  // count masked keys for this batch (once per block)
  {
    const int4* mr = (const int4*)(mask + bidx * 2048);
    int4 a = mr[t * 2], b = mr[t * 2 + 1];
    int cnt = (a.x == 0) + (a.y == 0) + (a.z == 0) + (a.w == 0) +
              (b.x == 0) + (b.y == 0) + (b.z == 0) + (b.w == 0);
    cnt += __shfl_xor(cnt, 1);  cnt += __shfl_xor(cnt, 2);
    cnt += __shfl_xor(cnt, 4);  cnt += __shfl_xor(cnt, 8);
    cnt += __shfl_xor(cnt, 16); cnt += __shfl_xor(cnt, 32);
    if (lane == 0) nmw[wave] = (float)cnt;
  }

  // Q fragments (B-operand), loop-invariant; wave covers 64 q rows (it 0..3)
  bf16x8 qf[2][4];
#pragma unroll
  for (int ks = 0; ks < 2; ++ks)
#pragma unroll
    for (int it = 0; it < 4; ++it)
      qf[ks][it] =
          *(const bf16x8*)&Qg[(wave * 64 + it * 16 + c) * 64 + ks * 32 + quad * 8];

  const bf16x8 ones = {0x3F80, 0x3F80, 0x3F80, 0x3F80,
                       0x3F80, 0x3F80, 0x3F80, 0x3F80};  // bf16 1.0 x8

  f32x4 zero4 = {0.f, 0.f, 0.f, 0.f};
  f32x4 O[4][4];
#pragma unroll
  for (int dt = 0; dt < 4; ++dt)
#pragma unroll
    for (int it = 0; it < 4; ++it) O[dt][it] = zero4;
  f32x4 Ol[4] = {zero4, zero4, zero4, zero4};

  const int krow0 = t >> 3;
  const int klc = (t & 7) ^ (krow0 & 7);
  const short* gk0 = Kg + (size_t)krow0 * 64 + klc * 8;
  const short* gv0 = Vg + (size_t)krow0 * 2048 + klc * 8;
  short* Pw = &Pl[wave][0];

  // prologue: stage chunk 0 into buffer 0
  gld_lds16(gk0, &Ks[0][t * 8]);
  gld_lds16(gk0 + 32 * 64, &Ks[0][t * 8 + 2048]);
  gld_lds16(gv0, &Vs[0][t * 8]);
  gld_lds16(gv0 + 32 * 2048, &Vs[0][t * 8 + 2048]);

  for (int ci = 0; ci < 32; ++ci) {
    __syncthreads();  // drains chunk-ci loads (issued one compute-phase ago)
    if (ci < 31) {
      int cn = (ci + 1) * 64;
      int nb = (ci + 1) & 1;
      gld_lds16(gk0 + (size_t)cn * 64, &Ks[nb][t * 8]);
      gld_lds16(gk0 + (size_t)(cn + 32) * 64, &Ks[nb][t * 8 + 2048]);
      gld_lds16(gv0 + cn, &Vs[nb][t * 8]);
      gld_lds16(gv0 + cn + 32 * 2048, &Vs[nb][t * 8 + 2048]);
    }
    const short* ksb = &Ks[ci & 1][0];
    const short* vsb = &Vs[ci & 1][0];

#pragma unroll
    for (int h = 0; h < 2; ++h) {  // two q-halves (it = 2h, 2h+1)
      f32x4 St[4][2];
#pragma unroll
      for (int jt = 0; jt < 4; ++jt) {
        bf16x8 ak =
            *(const bf16x8*)&ksb[(jt * 16 + c) * 64 + ((quad ^ (c & 7)) * 8)];
        St[jt][0] = MFMA16(ak, qf[0][h * 2 + 0], zero4);
        St[jt][1] = MFMA16(ak, qf[0][h * 2 + 1], zero4);
      }
#pragma unroll
      for (int jt = 0; jt < 4; ++jt) {
        bf16x8 ak =
            *(const bf16x8*)&ksb[(jt * 16 + c) * 64 + (((4 + quad) ^ (c & 7)) * 8)];
        St[jt][0] = MFMA16(ak, qf[1][h * 2 + 0], St[jt][0]);
        St[jt][1] = MFMA16(ak, qf[1][h * 2 + 1], St[jt][1]);
      }

#pragma unroll
      for (int itl = 0; itl < 2; ++itl) {
#pragma unroll
        for (int jt = 0; jt < 4; ++jt) {
          float p0 = FEXP(St[jt][itl][0]);
          float p1 = FEXP(St[jt][itl][1]);
          float p2 = FEXP(St[jt][itl][2]);
          float p3 = FEXP(St[jt][itl][3]);
          uint2v pk;
          pk[0] = pack_trunc(p0, p1);
          pk[1] = pack_trunc(p2, p3);
          *(uint2v*)&Pw[(itl * 16 + c) * 64 +
                        (((jt * 2 + (quad >> 1)) ^ (c & 7)) * 8) +
                        (quad & 1) * 4] = pk;
        }
      }
      asm volatile("s_waitcnt lgkmcnt(0)" ::: "memory");  // own-wave P visible

#pragma unroll
      for (int ks = 0; ks < 2; ++ks) {
        bf16x8 bp0 =
            *(const bf16x8*)&Pw[c * 64 + (((ks * 4 + quad) ^ (c & 7)) * 8)];
        bf16x8 bp1 =
            *(const bf16x8*)&Pw[(16 + c) * 64 + (((ks * 4 + quad) ^ (c & 7)) * 8)];
        Ol[h * 2 + 0] = MFMA16(ones, bp0, Ol[h * 2 + 0]);
        Ol[h * 2 + 1] = MFMA16(ones, bp1, Ol[h * 2 + 1]);
#pragma unroll
        for (int dt = 0; dt < 4; ++dt) {
          bf16x8 av =
              *(const bf16x8*)&vsb[(dt * 16 + c) * 64 + (((4 * ks + quad) ^ (c & 7)) * 8)];
          O[dt][h * 2 + 0] = MFMA16(av, bp0, O[dt][h * 2 + 0]);
          O[dt][h * 2 + 1] = MFMA16(av, bp1, O[dt][h * 2 + 1]);
        }
      }
    }
  }

  float nm = nmw[0] + nmw[1] + nmw[2] + nmw[3];
#pragma unroll
  for (int it = 0; it < 4; ++it) {
    float inv = 1.0f / (Ol[it][0] - nm);  // remove masked keys' exp2(0)=1
    int tq = qt * 256 + wave * 64 + it * 16 + c;
    size_t rb = ((size_t)bidx * 2048 + tq) * 1024 + (size_t)(bh & 15) * 64;
#pragma unroll
    for (int dt = 0; dt < 4; ++dt) {
      short4v ov;
#pragma unroll
      for (int r = 0; r < 4; ++r) ov[r] = f2bf(O[dt][it][r] * inv);
      *(short4v*)&Og[rb + dt * 16 + quad * 4] = ov;
    }
  }
}

// ---------------------------------------------------------------------------
// Kernel 4: output projection GEMM: out = attout @ Wo^T + bo (fp32 out).
//   64x128 tile, BK=32, double-buffered staging -> 1024 blocks, 24 KB LDS.
// ---------------------------------------------------------------------------
__global__ __launch_bounds__(256) void out_gemm(
    const short* __restrict__ Ab, const short* __restrict__ Wob,
    const float* __restrict__ bo, float* __restrict__ out) {
  __shared__ __align__(16) short As[2][64 * 32];   // 8 KB
  __shared__ __align__(16) short Bs[2][128 * 32];  // 16 KB

  const int t = threadIdx.x;
  const int lane = t & 63;
  const int wave = t >> 6;
  const int c = lane & 15;
  const int quad = lane >> 4;
  const int m0 = blockIdx.x * 64;
  const int n0 = blockIdx.y * 128;

  f32x4 zero4 = {0.f, 0.f, 0.f, 0.f};
  f32x4 acc[4][2];
#pragma unroll
  for (int i = 0; i < 4; ++i) {
    acc[i][0] = zero4;
    acc[i][1] = zero4;
  }

  const int srow = t >> 2;
  const int gc = ((t & 3) - (srow >> 2)) & 3;
  const short* gA = Ab + (size_t)(m0 + srow) * 1024 + gc * 8;
  const short* gB = Wob + (size_t)(n0 + srow) * 1024 + gc * 8;

#define OUT_STAGE(buf, k0)                                   \
  do {                                                       \
    gld_lds16(gA + (k0), &As[buf][t * 8]);                   \
    gld_lds16(gB + (k0), &Bs[buf][t * 8]);                   \
    gld_lds16(gB + (k0) + 65536, &Bs[buf][t * 8 + 2048]);    \
  } while (0)

  OUT_STAGE(0, 0);

  for (int ki = 0; ki < 32; ++ki) {
    __syncthreads();
    if (ki < 31) OUT_STAGE((ki + 1) & 1, (ki + 1) * 32);

    const short* as = &As[ki & 1][0];
    const short* bs = &Bs[ki & 1][0];
    bf16x8 af[4], bfr[2];
#pragma unroll
    for (int i = 0; i < 4; ++i) {
      int mr = i * 16 + c;
      af[i] = *(const bf16x8*)&as[mr * 32 + (((quad + (mr >> 2)) & 3) * 8)];
    }
#pragma unroll
    for (int j = 0; j < 2; ++j) {
      int nr = wave * 32 + j * 16 + c;
      bfr[j] = *(const bf16x8*)&bs[nr * 32 + (((quad + (nr >> 2)) & 3) * 8)];
    }
#pragma unroll
    for (int i = 0; i < 4; ++i) {
      acc[i][0] = MFMA16(af[i], bfr[0], acc[i][0]);
      acc[i][1] = MFMA16(af[i], bfr[1], acc[i][1]);
    }
  }
#undef OUT_STAGE

  const int nb = n0 + wave * 32;
  float bj[2];
  bj[0] = bo[nb + c];
  bj[1] = bo[nb + 16 + c];
#pragma unroll
  for (int i = 0; i < 4; ++i) {
    int m = m0 + i * 16 + quad * 4;
#pragma unroll
    for (int r = 0; r < 4; ++r) {
      float* orow = out + (size_t)(m + r) * 1024 + nb;
      orow[c]      = acc[i][0][r] + bj[0];
      orow[16 + c] = acc[i][1][r] + bj[1];
    }
  }
}

// ---------------------------------------------------------------------------
extern "C" void kernel_launch(void* const* d_in, const int* in_sizes, int n_in,
                              void* d_out, int out_size, void* d_ws,
                              size_t ws_size, hipStream_t stream) {
  const float* x    = (const float*)d_in[0];
  const float* rope = (const float*)d_in[1];
  const int*   mask = (const int*)d_in[2];
  const float* Wq   = (const float*)d_in[3];
  const float* bq   = (const float*)d_in[4];
  const float* Wk   = (const float*)d_in[5];
  const float* bk   = (const float*)d_in[6];
  const float* Wv   = (const float*)d_in[7];
  const float* bv   = (const float*)d_in[8];
  const float* Wo   = (const float*)d_in[9];
  const float* bo   = (const float*)d_in[10];
  float* out = (float*)d_out;

  char* ws = (char*)d_ws;
  short* xb  = (short*)(ws);               // 16 MB; reused as attout later
  short* wqb = (short*)(ws + 16777216);    // 2 MB each
  short* wkb = (short*)(ws + 18874368);
  short* wvb = (short*)(ws + 20971520);
  short* wob = (short*)(ws + 23068672);
  short* Qh  = (short*)(ws + 25198592);    // 16 MB  [bh][t][64]
  short* Kh  = (short*)(ws + 41975808);    // 16 MB  [bh][t][64]
  short* Vt  = (short*)(ws + 58753024);    // 16 MB  [bh][64][t]
  short* att = xb;  // safe: xb consumed by qkv3_gemm before attn writes

  cvt_kernel<<<12288, 256, 0, stream>>>(x, Wq, Wk, Wv, Wo, xb, wqb, wkb, wvb,
                                        wob);
  qkv3_gemm<<<dim3(64, 8), 256, 0, stream>>>(xb, wqb, wkb, wvb, bq, bk, bv,
                                             rope, mask, Qh, Kh, Vt);
  attn_kernel<<<dim3(8, 64), 256, 0, stream>>>(Qh, Kh, Vt, mask, att);
  out_gemm<<<dim3(128, 8), 256, 0, stream>>>(att, wob, bo, out);
}

// Round 7
// 278.023 us; speedup vs baseline: 1.0751x; 1.0097x over previous
//
#include <hip/hip_runtime.h>
#include <stdint.h>

// B=4, T=2048, C=1024, H=16, D=64, R=32
// Pipeline: cvt -> qkv3_gemm(fused QKV, dbuf) -> attn(hoisted K/V frags) -> out_gemm(dbuf)

typedef __attribute__((ext_vector_type(8))) short bf16x8;   // 8 bf16 (4 VGPRs)
typedef __attribute__((ext_vector_type(4))) float f32x4;    // MFMA accumulator
typedef __attribute__((ext_vector_type(4))) short short4v;  // 8-byte packed store
typedef __attribute__((ext_vector_type(2))) uint32_t uint2v;

#define MFMA16(a, b, c) __builtin_amdgcn_mfma_f32_16x16x32_bf16((a), (b), (c), 0, 0, 0)

#if __has_builtin(__builtin_amdgcn_exp2f)
#define FEXP(x) __builtin_amdgcn_exp2f(x)
#define QSCALE 0.18033688011112042f  // 0.125 * log2(e)
#else
#define FEXP(x) __expf(x)
#define QSCALE 0.125f
#endif

static __device__ __forceinline__ short f2bf(float f) {
  union { float fv; uint32_t u; } v; v.fv = f;
  uint32_t r = v.u + 0x7FFFu + ((v.u >> 16) & 1u);  // RNE
  return (short)(r >> 16);
}

// pack two fp32 -> two bf16 (truncation) in one v_perm_b32
static __device__ __forceinline__ uint32_t pack_trunc(float a, float b) {
  union { float f; uint32_t u; } ua, ub;
  ua.f = a; ub.f = b;
#if __has_builtin(__builtin_amdgcn_perm)
  return __builtin_amdgcn_perm(ub.u, ua.u, 0x07060302u);
#else
  return (ub.u & 0xFFFF0000u) | (ua.u >> 16);
#endif
}

typedef __attribute__((address_space(1))) void as1_void;
typedef __attribute__((address_space(3))) void as3_void;
static __device__ __forceinline__ void gld_lds16(const void* g, void* l) {
  __builtin_amdgcn_global_load_lds((as1_void*)g, (as3_void*)l, 16, 0, 0);
}

// ---------------------------------------------------------------------------
// Kernel 1: fp32 -> bf16 conversion for x, Wq, Wk, Wv, Wo
// ---------------------------------------------------------------------------
__global__ __launch_bounds__(256) void cvt_kernel(
    const float* x, const float* wq, const float* wk, const float* wv,
    const float* wo,
    short* xb, short* wqb, short* wkb, short* wvb, short* wob) {
  int64_t g = (int64_t)blockIdx.x * 256 + threadIdx.x;  // unit = 4 floats
  const int64_t NX = 8388608 / 4, NW = 1048576 / 4;
  const float* src;
  short* dst;
  int64_t i;
  if (g < NX)               { src = x;  dst = xb;  i = g; }
  else if (g < NX + NW)     { src = wq; dst = wqb; i = g - NX; }
  else if (g < NX + 2 * NW) { src = wk; dst = wkb; i = g - NX - NW; }
  else if (g < NX + 3 * NW) { src = wv; dst = wvb; i = g - NX - 2 * NW; }
  else                      { src = wo; dst = wob; i = g - NX - 3 * NW; }
  float4 v = ((const float4*)src)[i];
  short4v o;
  o[0] = f2bf(v.x); o[1] = f2bf(v.y); o[2] = f2bf(v.z); o[3] = f2bf(v.w);
  *(short4v*)&dst[i * 4] = o;
}

// ---------------------------------------------------------------------------
// Kernel 2: fused QKV projection (M=8192, N=1024 x3, K=1024), BK=32.
//   One A-tile stage feeds 3 B-tiles: 48 MFMA per barrier. Double-buffered
//   staging issued right after the barrier.
//   Q: scaled by QSCALE; K,V: masked rows zeroed.
//   Q,K written [bh][t][64] bf16; V written [bh][64][t] bf16 (transposed).
// ---------------------------------------------------------------------------
__global__ __launch_bounds__(256, 2) void qkv3_gemm(
    const short* __restrict__ Xb,
    const short* __restrict__ Wq, const short* __restrict__ Wk,
    const short* __restrict__ Wv,
    const float* __restrict__ bq, const float* __restrict__ bk,
    const float* __restrict__ bv,
    const float* __restrict__ rope, const int* __restrict__ mask,
    short* __restrict__ Qh, short* __restrict__ Kh, short* __restrict__ Vt) {
  __shared__ __align__(16) short As[2][128 * 32];     // 16 KB
  __shared__ __align__(16) short Bs[2][3][128 * 32];  // 48 KB

  const int t = threadIdx.x;
  const int lane = t & 63;
  const int wave = t >> 6;
  const int c = lane & 15;
  const int quad = lane >> 4;
  const int m0 = blockIdx.x * 128;
  const int n0 = blockIdx.y * 128;

  f32x4 zero4 = {0.f, 0.f, 0.f, 0.f};
  f32x4 acc[3][4][4];
#pragma unroll
  for (int m = 0; m < 3; ++m)
#pragma unroll
    for (int i = 0; i < 4; ++i)
#pragma unroll
      for (int j = 0; j < 4; ++j) acc[m][i][j] = zero4;

  const int wm = wave & 1, wn = wave >> 1;

  const int srow = t >> 2;
  const int gc = ((t & 3) - (srow >> 2)) & 3;
  const short* gA = Xb + (size_t)(m0 + srow) * 1024 + gc * 8;
  const short* gW0 = Wq + (size_t)(n0 + srow) * 1024 + gc * 8;
  const short* gW1 = Wk + (size_t)(n0 + srow) * 1024 + gc * 8;
  const short* gW2 = Wv + (size_t)(n0 + srow) * 1024 + gc * 8;

#define QKV_STAGE(buf, k0)                                  \
  do {                                                      \
    gld_lds16(gA + (k0), &As[buf][t * 8]);                  \
    gld_lds16(gA + (k0) + 65536, &As[buf][t * 8 + 2048]);   \
    gld_lds16(gW0 + (k0), &Bs[buf][0][t * 8]);              \
    gld_lds16(gW0 + (k0) + 65536, &Bs[buf][0][t * 8 + 2048]); \
    gld_lds16(gW1 + (k0), &Bs[buf][1][t * 8]);              \
    gld_lds16(gW1 + (k0) + 65536, &Bs[buf][1][t * 8 + 2048]); \
    gld_lds16(gW2 + (k0), &Bs[buf][2][t * 8]);              \
    gld_lds16(gW2 + (k0) + 65536, &Bs[buf][2][t * 8 + 2048]); \
  } while (0)

  QKV_STAGE(0, 0);

  for (int ki = 0; ki < 32; ++ki) {
    __syncthreads();  // drains buf[ki&1] loads (issued one compute phase ago)
    if (ki < 31) QKV_STAGE((ki + 1) & 1, (ki + 1) * 32);

    const short* as = &As[ki & 1][0];
    bf16x8 af[4];
#pragma unroll
    for (int i = 0; i < 4; ++i) {
      int mr = wm * 64 + i * 16 + c;
      af[i] = *(const bf16x8*)&as[mr * 32 + (((quad + (mr >> 2)) & 3) * 8)];
    }
#pragma unroll
    for (int m = 0; m < 3; ++m) {
      const short* bs = &Bs[ki & 1][m][0];
      bf16x8 bfr[4];
#pragma unroll
      for (int j = 0; j < 4; ++j) {
        int nr = wn * 64 + j * 16 + c;
        bfr[j] = *(const bf16x8*)&bs[nr * 32 + (((quad + (nr >> 2)) & 3) * 8)];
      }
#pragma unroll
      for (int i = 0; i < 4; ++i)
#pragma unroll
        for (int j = 0; j < 4; ++j)
          acc[m][i][j] = MFMA16(af[i], bfr[j], acc[m][i][j]);
    }
  }
#undef QKV_STAGE

  // ---- epilogue: C/D layout col=lane&15, row=quad*4+reg ----
  const int nb = n0 + wn * 64;  // wave's 64 cols == one head
  const int hcol = nb >> 6;
  const int bidx = m0 >> 11;
  const int tbase = (m0 & 2047) + wm * 64 + quad * 4;
  const int* mrow = mask + bidx * 2048;

  // Q (mat 0) and K (mat 1): [bh][t][64] with RoPE
#pragma unroll
  for (int mat = 0; mat < 2; ++mat) {
    short* Og = (mat == 0) ? Qh : Kh;
    const float* bias = (mat == 0) ? bq : bk;
    float bj[4];
#pragma unroll
    for (int j = 0; j < 4; ++j) bj[j] = bias[nb + j * 16 + c];
    size_t hb = (size_t)(bidx * 16 + hcol) * 2048;
#pragma unroll
    for (int i = 0; i < 4; ++i) {
#pragma unroll
      for (int r = 0; r < 4; ++r) {
        int tp = tbase + i * 16 + r;
        float f = (mat == 0) ? QSCALE : (mrow[tp] ? 1.0f : 0.0f);
        float cosv = rope[tp * 32 + c];
        float sinv = rope[65536 + tp * 32 + c];
        float v0 = acc[mat][i][0][r] + bj[0];
        float v1 = acc[mat][i][1][r] + bj[1];
        float v2 = acc[mat][i][2][r] + bj[2];
        float v3 = acc[mat][i][3][r] + bj[3];
        size_t base = (hb + tp) * 64;
        Og[base + c]      = f2bf((v0 * cosv - v1 * sinv) * f);
        Og[base + 16 + c] = f2bf((v1 * cosv + v0 * sinv) * f);
        Og[base + 32 + c] = f2bf(v2 * f);
        Og[base + 48 + c] = f2bf(v3 * f);
      }
    }
  }
  // V (mat 2): transposed [bh][d][t], masked t zeroed
  {
    float bj[4];
#pragma unroll
    for (int j = 0; j < 4; ++j) bj[j] = bv[nb + j * 16 + c];
    size_t hb = (size_t)(bidx * 16 + hcol) * 64;
#pragma unroll
    for (int i = 0; i < 4; ++i) {
      int tp = tbase + i * 16;  // multiple of 4
      int4 mv = *(const int4*)&mrow[tp];
      float fr[4];
      fr[0] = mv.x ? 1.f : 0.f; fr[1] = mv.y ? 1.f : 0.f;
      fr[2] = mv.z ? 1.f : 0.f; fr[3] = mv.w ? 1.f : 0.f;
#pragma unroll
      for (int j = 0; j < 4; ++j) {
        short4v pv;
#pragma unroll
        for (int r = 0; r < 4; ++r)
          pv[r] = f2bf((acc[2][i][j][r] + bj[j]) * fr[r]);
        size_t base = (hb + j * 16 + c) * 2048 + tp;
        *(short4v*)&Vt[base] = pv;
      }
    }
  }
}

// ---------------------------------------------------------------------------
// Kernel 3: attention, static softmax. 256 q-rows/block (64 per wave),
//   double-buffered K/V staging; K and V fragments hoisted to registers
//   once per chunk (shared by both q-halves -> 40->24 b128 LDS reads/chunk).
//   S^T = K*Q^T -> p = exp2(s) -> P(bf16) -> O^T = V^T*P^T; l via ones-A MFMA.
// ---------------------------------------------------------------------------
__global__ __launch_bounds__(256, 2) void attn_kernel(
    const short* __restrict__ Qh, const short* __restrict__ Kh,
    const short* __restrict__ Vt, const int* __restrict__ mask,
    short* __restrict__ Og) {
  __shared__ __align__(16) short Ks[2][64 * 64];  // 16 KB
  __shared__ __align__(16) short Vs[2][64 * 64];  // 16 KB
  __shared__ __align__(16) short Pl[4][32 * 64];  // 16 KB, per-wave
  __shared__ float nmw[4];

  const int t = threadIdx.x;
  const int lane = t & 63;
  const int wave = t >> 6;
  const int c = lane & 15;
  const int quad = lane >> 4;
  const int qt = blockIdx.x;   // 0..7 (256 q rows each)
  const int bh = blockIdx.y;   // 0..63
  const int bidx = bh >> 4;
  const short* Qg = Qh + ((size_t)bh * 2048 + qt * 256) * 64;
  const short* Kg = Kh + (size_t)bh * 2048 * 64;
  const short* Vg = Vt + (size_t)bh * 64 * 2048;

  // count masked keys for this batch (once per block)
  {
    const int4* mr = (const int4*)(mask + bidx * 2048);
    int4 a = mr[t * 2], b = mr[t * 2 + 1];
    int cnt = (a.x == 0) + (a.y == 0) + (a.z == 0) + (a.w == 0) +
              (b.x == 0) + (b.y == 0) + (b.z == 0) + (b.w == 0);
    cnt += __shfl_xor(cnt, 1);  cnt += __shfl_xor(cnt, 2);
    cnt += __shfl_xor(cnt, 4);  cnt += __shfl_xor(cnt, 8);
    cnt += __shfl_xor(cnt, 16); cnt += __shfl_xor(cnt, 32);
    if (lane == 0) nmw[wave] = (float)cnt;
  }

  // Q fragments (B-operand), loop-invariant; wave covers 64 q rows (it 0..3)
  bf16x8 qf[2][4];
#pragma unroll
  for (int ks = 0; ks < 2; ++ks)
#pragma unroll
    for (int it = 0; it < 4; ++it)
      qf[ks][it] =
          *(const bf16x8*)&Qg[(wave * 64 + it * 16 + c) * 64 + ks * 32 + quad * 8];

  const bf16x8 ones = {0x3F80, 0x3F80, 0x3F80, 0x3F80,
                       0x3F80, 0x3F80, 0x3F80, 0x3F80};  // bf16 1.0 x8

  f32x4 zero4 = {0.f, 0.f, 0.f, 0.f};
  f32x4 O[4][4];
#pragma unroll
  for (int dt = 0; dt < 4; ++dt)
#pragma unroll
    for (int it = 0; it < 4; ++it) O[dt][it] = zero4;
  f32x4 Ol[4] = {zero4, zero4, zero4, zero4};

  const int krow0 = t >> 3;
  const int klc = (t & 7) ^ (krow0 & 7);
  const short* gk0 = Kg + (size_t)krow0 * 64 + klc * 8;
  const short* gv0 = Vg + (size_t)krow0 * 2048 + klc * 8;
  short* Pw = &Pl[wave][0];

  // prologue: stage chunk 0 into buffer 0
  gld_lds16(gk0, &Ks[0][t * 8]);
  gld_lds16(gk0 + 32 * 64, &Ks[0][t * 8 + 2048]);
  gld_lds16(gv0, &Vs[0][t * 8]);
  gld_lds16(gv0 + 32 * 2048, &Vs[0][t * 8 + 2048]);

  for (int ci = 0; ci < 32; ++ci) {
    __syncthreads();  // drains chunk-ci loads (issued one compute-phase ago)
    if (ci < 31) {
      int cn = (ci + 1) * 64;
      int nb = (ci + 1) & 1;
      gld_lds16(gk0 + (size_t)cn * 64, &Ks[nb][t * 8]);
      gld_lds16(gk0 + (size_t)(cn + 32) * 64, &Ks[nb][t * 8 + 2048]);
      gld_lds16(gv0 + cn, &Vs[nb][t * 8]);
      gld_lds16(gv0 + cn + 32 * 2048, &Vs[nb][t * 8 + 2048]);
    }
    const short* ksb = &Ks[ci & 1][0];
    const short* vsb = &Vs[ci & 1][0];

    // hoisted K/V fragments (shared by both q-halves)
    bf16x8 ak[2][4], av[2][4];
#pragma unroll
    for (int ks = 0; ks < 2; ++ks)
#pragma unroll
      for (int jt = 0; jt < 4; ++jt) {
        ak[ks][jt] = *(const bf16x8*)&ksb[(jt * 16 + c) * 64 +
                                          (((4 * ks + quad) ^ (c & 7)) * 8)];
        av[ks][jt] = *(const bf16x8*)&vsb[(jt * 16 + c) * 64 +
                                          (((4 * ks + quad) ^ (c & 7)) * 8)];
      }

#pragma unroll
    for (int h = 0; h < 2; ++h) {  // two q-halves (it = 2h, 2h+1)
      f32x4 St[4][2];
#pragma unroll
      for (int jt = 0; jt < 4; ++jt) {
        St[jt][0] = MFMA16(ak[0][jt], qf[0][h * 2 + 0], zero4);
        St[jt][1] = MFMA16(ak[0][jt], qf[0][h * 2 + 1], zero4);
      }
#pragma unroll
      for (int jt = 0; jt < 4; ++jt) {
        St[jt][0] = MFMA16(ak[1][jt], qf[1][h * 2 + 0], St[jt][0]);
        St[jt][1] = MFMA16(ak[1][jt], qf[1][h * 2 + 1], St[jt][1]);
      }

#pragma unroll
      for (int itl = 0; itl < 2; ++itl) {
#pragma unroll
        for (int jt = 0; jt < 4; ++jt) {
          float p0 = FEXP(St[jt][itl][0]);
          float p1 = FEXP(St[jt][itl][1]);
          float p2 = FEXP(St[jt][itl][2]);
          float p3 = FEXP(St[jt][itl][3]);
          uint2v pk;
          pk[0] = pack_trunc(p0, p1);
          pk[1] = pack_trunc(p2, p3);
          *(uint2v*)&Pw[(itl * 16 + c) * 64 +
                        (((jt * 2 + (quad >> 1)) ^ (c & 7)) * 8) +
                        (quad & 1) * 4] = pk;
        }
      }
      asm volatile("s_waitcnt lgkmcnt(0)" ::: "memory");  // own-wave P visible

#pragma unroll
      for (int ks = 0; ks < 2; ++ks) {
        bf16x8 bp0 =
            *(const bf16x8*)&Pw[c * 64 + (((ks * 4 + quad) ^ (c & 7)) * 8)];
        bf16x8 bp1 =
            *(const bf16x8*)&Pw[(16 + c) * 64 + (((ks * 4 + quad) ^ (c & 7)) * 8)];
        Ol[h * 2 + 0] = MFMA16(ones, bp0, Ol[h * 2 + 0]);
        Ol[h * 2 + 1] = MFMA16(ones, bp1, Ol[h * 2 + 1]);
#pragma unroll
        for (int dt = 0; dt < 4; ++dt) {
          O[dt][h * 2 + 0] = MFMA16(av[ks][dt], bp0, O[dt][h * 2 + 0]);
          O[dt][h * 2 + 1] = MFMA16(av[ks][dt], bp1, O[dt][h * 2 + 1]);
        }
      }
    }
  }

  float nm = nmw[0] + nmw[1] + nmw[2] + nmw[3];
#pragma unroll
  for (int it = 0; it < 4; ++it) {
    float inv = 1.0f / (Ol[it][0] - nm);  // remove masked keys' exp2(0)=1
    int tq = qt * 256 + wave * 64 + it * 16 + c;
    size_t rb = ((size_t)bidx * 2048 + tq) * 1024 + (size_t)(bh & 15) * 64;
#pragma unroll
    for (int dt = 0; dt < 4; ++dt) {
      short4v ov;
#pragma unroll
      for (int r = 0; r < 4; ++r) ov[r] = f2bf(O[dt][it][r] * inv);
      *(short4v*)&Og[rb + dt * 16 + quad * 4] = ov;
    }
  }
}

// ---------------------------------------------------------------------------
// Kernel 4: output projection GEMM: out = attout @ Wo^T + bo (fp32 out).
//   64x128 tile, BK=32, double-buffered staging -> 1024 blocks, 24 KB LDS.
// ---------------------------------------------------------------------------
__global__ __launch_bounds__(256) void out_gemm(
    const short* __restrict__ Ab, const short* __restrict__ Wob,
    const float* __restrict__ bo, float* __restrict__ out) {
  __shared__ __align__(16) short As[2][64 * 32];   // 8 KB
  __shared__ __align__(16) short Bs[2][128 * 32];  // 16 KB

  const int t = threadIdx.x;
  const int lane = t & 63;
  const int wave = t >> 6;
  const int c = lane & 15;
  const int quad = lane >> 4;
  const int m0 = blockIdx.x * 64;
  const int n0 = blockIdx.y * 128;

  f32x4 zero4 = {0.f, 0.f, 0.f, 0.f};
  f32x4 acc[4][2];
#pragma unroll
  for (int i = 0; i < 4; ++i) {
    acc[i][0] = zero4;
    acc[i][1] = zero4;
  }

  const int srow = t >> 2;
  const int gc = ((t & 3) - (srow >> 2)) & 3;
  const short* gA = Ab + (size_t)(m0 + srow) * 1024 + gc * 8;
  const short* gB = Wob + (size_t)(n0 + srow) * 1024 + gc * 8;

#define OUT_STAGE(buf, k0)                                   \
  do {                                                       \
    gld_lds16(gA + (k0), &As[buf][t * 8]);                   \
    gld_lds16(gB + (k0), &Bs[buf][t * 8]);                   \
    gld_lds16(gB + (k0) + 65536, &Bs[buf][t * 8 + 2048]);    \
  } while (0)

  OUT_STAGE(0, 0);

  for (int ki = 0; ki < 32; ++ki) {
    __syncthreads();
    if (ki < 31) OUT_STAGE((ki + 1) & 1, (ki + 1) * 32);

    const short* as = &As[ki & 1][0];
    const short* bs = &Bs[ki & 1][0];
    bf16x8 af[4], bfr[2];
#pragma unroll
    for (int i = 0; i < 4; ++i) {
      int mr = i * 16 + c;
      af[i] = *(const bf16x8*)&as[mr * 32 + (((quad + (mr >> 2)) & 3) * 8)];
    }
#pragma unroll
    for (int j = 0; j < 2; ++j) {
      int nr = wave * 32 + j * 16 + c;
      bfr[j] = *(const bf16x8*)&bs[nr * 32 + (((quad + (nr >> 2)) & 3) * 8)];
    }
#pragma unroll
    for (int i = 0; i < 4; ++i) {
      acc[i][0] = MFMA16(af[i], bfr[0], acc[i][0]);
      acc[i][1] = MFMA16(af[i], bfr[1], acc[i][1]);
    }
  }
#undef OUT_STAGE

  const int nb = n0 + wave * 32;
  float bj[2];
  bj[0] = bo[nb + c];
  bj[1] = bo[nb + 16 + c];
#pragma unroll
  for (int i = 0; i < 4; ++i) {
    int m = m0 + i * 16 + quad * 4;
#pragma unroll
    for (int r = 0; r < 4; ++r) {
      float* orow = out + (size_t)(m + r) * 1024 + nb;
      orow[c]      = acc[i][0][r] + bj[0];
      orow[16 + c] = acc[i][1][r] + bj[1];
    }
  }
}

// ---------------------------------------------------------------------------
extern "C" void kernel_launch(void* const* d_in, const int* in_sizes, int n_in,
                              void* d_out, int out_size, void* d_ws,
                              size_t ws_size, hipStream_t stream) {
  const float* x    = (const float*)d_in[0];
  const float* rope = (const float*)d_in[1];
  const int*   mask = (const int*)d_in[2];
  const float* Wq   = (const float*)d_in[3];
  const float* bq   = (const float*)d_in[4];
  const float* Wk   = (const float*)d_in[5];
  const float* bk   = (const float*)d_in[6];
  const float* Wv   = (const float*)d_in[7];
  const float* bv   = (const float*)d_in[8];
  const float* Wo   = (const float*)d_in[9];
  const float* bo   = (const float*)d_in[10];
  float* out = (float*)d_out;

  char* ws = (char*)d_ws;
  short* xb  = (short*)(ws);               // 16 MB; reused as attout later
  short* wqb = (short*)(ws + 16777216);    // 2 MB each
  short* wkb = (short*)(ws + 18874368);
  short* wvb = (short*)(ws + 20971520);
  short* wob = (short*)(ws + 23068672);
  short* Qh  = (short*)(ws + 25198592);    // 16 MB  [bh][t][64]
  short* Kh  = (short*)(ws + 41975808);    // 16 MB  [bh][t][64]
  short* Vt  = (short*)(ws + 58753024);    // 16 MB  [bh][64][t]
  short* att = xb;  // safe: xb consumed by qkv3_gemm before attn writes

  cvt_kernel<<<12288, 256, 0, stream>>>(x, Wq, Wk, Wv, Wo, xb, wqb, wkb, wvb,
                                        wob);
  qkv3_gemm<<<dim3(64, 8), 256, 0, stream>>>(xb, wqb, wkb, wvb, bq, bk, bv,
                                             rope, mask, Qh, Kh, Vt);
  attn_kernel<<<dim3(8, 64), 256, 0, stream>>>(Qh, Kh, Vt, mask, att);
  out_gemm<<<dim3(128, 8), 256, 0, stream>>>(att, wob, bo, out);
}